// Round 1
// baseline (272.998 us; speedup 1.0000x reference)
//
#include <hip/hip_runtime.h>
#include <hip/hip_bf16.h>
#include <stdint.h>

// ---------------------------------------------------------------------------
// LinkPredictor: out = minmax_norm(E @ E^T)[block-diag strict upper triangle]
// N=16384 nodes (128 graphs x 128), D=512.
// Strategy: bf16 MFMA GEMM over upper-triangular 128x128 tiles for global
// min/max (symmetry halves work); diagonal tiles stored raw; normalize at
// gather time using provided row/col indices.
// ---------------------------------------------------------------------------

typedef __attribute__((ext_vector_type(8))) __bf16 bf16x8;
typedef __attribute__((ext_vector_type(4))) float floatx4;

#define AS1 __attribute__((address_space(1)))
#define AS3 __attribute__((address_space(3)))

static constexpr int DIM   = 512;
static constexpr int NTILE = 128;          // 16384 / 128 tiles per side

static __device__ __forceinline__ unsigned short f2bf_rne(float f) {
  unsigned int u = __float_as_uint(f);
  u += 0x7fffu + ((u >> 16) & 1u);
  return (unsigned short)(u >> 16);
}

// ---- kernel 1: fp32 -> bf16 ------------------------------------------------
__global__ void k_convert(const float* __restrict__ in,
                          unsigned short* __restrict__ out, int n4) {
  int i = blockIdx.x * blockDim.x + threadIdx.x;
  if (i >= n4) return;
  float4 v = ((const float4*)in)[i];
  ushort4 o;
  o.x = f2bf_rne(v.x); o.y = f2bf_rne(v.y);
  o.z = f2bf_rne(v.z); o.w = f2bf_rne(v.w);
  ((ushort4*)out)[i] = o;
}

// ---- kernel 2: tiled min/max GEMM (upper-triangular tiles) -----------------
// 128x128 tile per block, 256 threads = 4 waves (2x2 of 64x64), BK=64,
// 16x16x32 bf16 MFMA, global_load_lds(16B) staging with XOR chunk swizzle.
__global__ __launch_bounds__(256) void k_minmax_gemm(
    const unsigned short* __restrict__ E,
    float2* __restrict__ partials,
    float* __restrict__ diagblocks) {
  const int tc = blockIdx.x, tr = blockIdx.y;
  const int b  = tr * NTILE + tc;
  const int tid = threadIdx.x;
  if (tc < tr) {                 // lower triangle: symmetric, skip
    if (tid == 0) partials[b] = make_float2(3.4e38f, -3.4e38f);
    return;
  }

  __shared__ __align__(16) unsigned short lA[128 * 64];
  __shared__ __align__(16) unsigned short lB[128 * 64];
  __shared__ float2 redbuf[4];

  const int w = tid >> 6, lane = tid & 63;
  const int wr = w >> 1, wc = w & 1;           // wave at (wr,wc) of 2x2
  const int frow = lane & 15;                  // MFMA m/n index
  const int fq   = lane >> 4;                  // MFMA k-quad

  floatx4 acc[4][4];
#pragma unroll
  for (int i = 0; i < 4; i++)
#pragma unroll
    for (int j = 0; j < 4; j++) acc[i][j] = (floatx4){0.f, 0.f, 0.f, 0.f};

  const int rowBaseA = tr * 128;
  const int rowBaseB = tc * 128;

  for (int kb = 0; kb < 8; kb++) {             // K = 512 = 8 * BK(64)
    const int kBase = kb * 64;
    // stage both tiles: 128 rows x 8 chunks(16B). chunk stored at
    // (row, c8) holds global chunk (row, c8 ^ (row&7))  -> conflict-free reads
#pragma unroll
    for (int j = 0; j < 4; j++) {
      int cb  = (w * 4 + j) * 64;              // wave-uniform chunk base
      int p   = cb + lane;
      int row = p >> 3, c8 = p & 7;
      int sc8 = c8 ^ (row & 7);
      const unsigned short* gA = E + (size_t)(rowBaseA + row) * DIM + kBase + sc8 * 8;
      const unsigned short* gB = E + (size_t)(rowBaseB + row) * DIM + kBase + sc8 * 8;
      __builtin_amdgcn_global_load_lds((const AS1 unsigned int*)gA,
                                       (AS3 unsigned int*)(lA + cb * 8), 16, 0, 0);
      __builtin_amdgcn_global_load_lds((const AS1 unsigned int*)gB,
                                       (AS3 unsigned int*)(lB + cb * 8), 16, 0, 0);
    }
    __syncthreads();

    bf16x8 af[4][2], bfr[4][2];
#pragma unroll
    for (int mi = 0; mi < 4; mi++) {
      int r = wr * 64 + mi * 16 + frow;
#pragma unroll
      for (int ks = 0; ks < 2; ks++) {
        int c8 = ks * 4 + fq;
        af[mi][ks] = *(const bf16x8*)(lA + (r * 8 + (c8 ^ (r & 7))) * 8);
      }
    }
#pragma unroll
    for (int ni = 0; ni < 4; ni++) {
      int r = wc * 64 + ni * 16 + frow;
#pragma unroll
      for (int ks = 0; ks < 2; ks++) {
        int c8 = ks * 4 + fq;
        bfr[ni][ks] = *(const bf16x8*)(lB + (r * 8 + (c8 ^ (r & 7))) * 8);
      }
    }
#pragma unroll
    for (int ks = 0; ks < 2; ks++)
#pragma unroll
      for (int mi = 0; mi < 4; mi++)
#pragma unroll
        for (int ni = 0; ni < 4; ni++)
          acc[mi][ni] = __builtin_amdgcn_mfma_f32_16x16x32_bf16(
              af[mi][ks], bfr[ni][ks], acc[mi][ni], 0, 0, 0);
    __syncthreads();
  }

  // per-block min/max
  float vmin = 3.4e38f, vmax = -3.4e38f;
#pragma unroll
  for (int mi = 0; mi < 4; mi++)
#pragma unroll
    for (int ni = 0; ni < 4; ni++)
#pragma unroll
      for (int r = 0; r < 4; r++) {
        float v = acc[mi][ni][r];
        vmin = fminf(vmin, v);
        vmax = fmaxf(vmax, v);
      }
#pragma unroll
  for (int m_ = 32; m_ >= 1; m_ >>= 1) {
    vmin = fminf(vmin, __shfl_xor(vmin, m_));
    vmax = fmaxf(vmax, __shfl_xor(vmax, m_));
  }
  if (lane == 0) redbuf[w] = make_float2(vmin, vmax);
  __syncthreads();
  if (tid == 0) {
    float mn = redbuf[0].x, mx = redbuf[0].y;
    for (int i = 1; i < 4; i++) {
      mn = fminf(mn, redbuf[i].x);
      mx = fmaxf(mx, redbuf[i].y);
    }
    partials[b] = make_float2(mn, mx);
  }

  // diagonal tile: store raw block (symmetric -> layout transpose-immune)
  if (tr == tc) {
    float* Bout = diagblocks + (size_t)tr * (128 * 128);
#pragma unroll
    for (int mi = 0; mi < 4; mi++) {
      int rbase = wr * 64 + mi * 16 + fq * 4;   // C/D: row = quad*4 + reg
#pragma unroll
      for (int ni = 0; ni < 4; ni++) {
        int c = wc * 64 + ni * 16 + frow;       // C/D: col = lane & 15
#pragma unroll
        for (int r = 0; r < 4; r++)
          Bout[(rbase + r) * 128 + c] = acc[mi][ni][r];
      }
    }
  }
}

// ---- kernel 3: reduce 16384 partials -> m, 1/(M-m+eps) ---------------------
__global__ void k_reduce(const float2* __restrict__ partials,
                         float* __restrict__ mm) {
  int tid = threadIdx.x;
  float mn = 3.4e38f, mx = -3.4e38f;
  for (int i = tid; i < NTILE * NTILE; i += 256) {
    float2 p = partials[i];
    mn = fminf(mn, p.x);
    mx = fmaxf(mx, p.y);
  }
#pragma unroll
  for (int m_ = 32; m_ >= 1; m_ >>= 1) {
    mn = fminf(mn, __shfl_xor(mn, m_));
    mx = fmaxf(mx, __shfl_xor(mx, m_));
  }
  __shared__ float2 red[4];
  int w = tid >> 6, lane = tid & 63;
  if (lane == 0) red[w] = make_float2(mn, mx);
  __syncthreads();
  if (tid == 0) {
    for (int i = 1; i < 4; i++) {
      mn = fminf(mn, red[i].x);
      mx = fmaxf(mx, red[i].y);
    }
    mm[0] = mn;
    mm[1] = 1.0f / (mx - mn + 1e-7f);
  }
}

// ---- kernel 4: gather + normalize -----------------------------------------
__global__ void k_gather(const int* __restrict__ rix, const int* __restrict__ cix,
                         const float* __restrict__ blocks,
                         const float* __restrict__ mm,
                         float* __restrict__ out, int n) {
  int i = blockIdx.x * blockDim.x + threadIdx.x;
  if (i >= n) return;
  float m = mm[0], inv = mm[1];
  int r = rix[i], c = cix[i];
  int g = r >> 7;
  float v = blocks[((size_t)g << 14) + ((r & 127) << 7) + (c & 127)];
  out[i] = (v - m) * inv;
}

// ---------------------------------------------------------------------------
extern "C" void kernel_launch(void* const* d_in, const int* in_sizes, int n_in,
                              void* d_out, int out_size, void* d_ws, size_t ws_size,
                              hipStream_t stream) {
  const float* emb = (const float*)d_in[0];
  const int* rix   = (const int*)d_in[1];
  const int* cix   = (const int*)d_in[2];

  char* ws = (char*)d_ws;
  float* mm             = (float*)ws;                                  // 8 B (pad 256)
  unsigned short* Ebf   = (unsigned short*)(ws + 256);                 // 16 MB
  float2* partials      = (float2*)(ws + 256 + (16u << 20));           // 128 KB
  float* diagblocks     = (float*)(ws + 256 + (16u << 20) + (128u << 10)); // 8 MB

  int n_elem = in_sizes[0];            // 16384*512
  int n4 = n_elem / 4;
  k_convert<<<(n4 + 255) / 256, 256, 0, stream>>>(emb, Ebf, n4);

  dim3 g2(NTILE, NTILE);
  k_minmax_gemm<<<g2, 256, 0, stream>>>(Ebf, partials, diagblocks);

  k_reduce<<<1, 256, 0, stream>>>(partials, mm);

  k_gather<<<(out_size + 255) / 256, 256, 0, stream>>>(rix, cix, diagblocks, mm,
                                                       (float*)d_out, out_size);
}

// Round 2
// 248.574 us; speedup vs baseline: 1.0983x; 1.0983x over previous
//
#include <hip/hip_runtime.h>
#include <hip/hip_bf16.h>
#include <stdint.h>
#include <math.h>

// ---------------------------------------------------------------------------
// LinkPredictor: out = minmax_norm(E @ E^T)[block-diag strict upper triangle]
// N=16384 (128 graphs x 128), D=512.
// R2: 32x32x16 MFMA (half the instrs, ~20% better pipe eff), 1D triangular
// grid (no dead blocks), fused reduce+gather.
// ---------------------------------------------------------------------------

typedef __attribute__((ext_vector_type(8))) __bf16 bf16x8;
typedef __attribute__((ext_vector_type(16))) float floatx16;

#define AS1 __attribute__((address_space(1)))
#define AS3 __attribute__((address_space(3)))

static constexpr int DIM    = 512;
static constexpr int NTILE  = 128;                    // tiles per side
static constexpr int NPART  = NTILE * (NTILE + 1) / 2; // 8256 upper-tri tiles

static __device__ __forceinline__ unsigned short f2bf_rne(float f) {
  unsigned int u = __float_as_uint(f);
  u += 0x7fffu + ((u >> 16) & 1u);
  return (unsigned short)(u >> 16);
}

// ---- kernel 1: fp32 -> bf16 ------------------------------------------------
__global__ void k_convert(const float* __restrict__ in,
                          unsigned short* __restrict__ out, int n4) {
  int i = blockIdx.x * blockDim.x + threadIdx.x;
  if (i >= n4) return;
  float4 v = ((const float4*)in)[i];
  ushort4 o;
  o.x = f2bf_rne(v.x); o.y = f2bf_rne(v.y);
  o.z = f2bf_rne(v.z); o.w = f2bf_rne(v.w);
  ((ushort4*)out)[i] = o;
}

// ---- kernel 2: tiled min/max GEMM over upper-triangular 128x128 tiles ------
// 256 thr = 4 waves (2x2), each wave 64x64 via 2x2 of 32x32x16 MFMA, BK=64,
// global_load_lds(16B) staging with XOR chunk swizzle.
__global__ __launch_bounds__(256) void k_minmax_gemm(
    const unsigned short* __restrict__ E,
    float2* __restrict__ partials,
    float* __restrict__ diagblocks) {
  // decode linear upper-triangle index -> (tr, tc), tc >= tr
  const int bi = blockIdx.x;
  int tr = (int)((257.0 - sqrt(66049.0 - 8.0 * (double)bi)) * 0.5);
  if (tr < 0) tr = 0;
  if (tr > 127) tr = 127;
  while (tr * (257 - tr) / 2 > bi) --tr;
  while (tr < 127 && (tr + 1) * (256 - tr) / 2 <= bi) ++tr;
  const int tc = tr + (bi - tr * (257 - tr) / 2);

  const int tid = threadIdx.x;
  __shared__ __align__(16) unsigned short lA[128 * 64];
  __shared__ __align__(16) unsigned short lB[128 * 64];
  __shared__ float2 redbuf[4];

  const int w = tid >> 6, lane = tid & 63;
  const int wr = w >> 1, wc = w & 1;           // wave at (wr,wc) of 2x2
  const int l31 = lane & 31;                   // MFMA 32x32 row/col index
  const int kg  = lane >> 5;                   // MFMA k-group (0/1)

  floatx16 acc[2][2];
#pragma unroll
  for (int i = 0; i < 2; i++)
#pragma unroll
    for (int j = 0; j < 2; j++)
#pragma unroll
      for (int r = 0; r < 16; r++) acc[i][j][r] = 0.f;

  const int rowBaseA = tr * 128;
  const int rowBaseB = tc * 128;

  for (int kb = 0; kb < 8; kb++) {             // K = 512 = 8 * BK(64)
    const int kBase = kb * 64;
    // stage A,B tiles: 128 rows x 8 chunks(16B); (row,c8) slot holds global
    // chunk (row, c8 ^ (row&7)) -> conflict-free fragment reads
#pragma unroll
    for (int j = 0; j < 4; j++) {
      int cb  = (w * 4 + j) * 64;              // wave-uniform chunk base
      int p   = cb + lane;
      int row = p >> 3, c8 = p & 7;
      int sc8 = c8 ^ (row & 7);
      const unsigned short* gA = E + (size_t)(rowBaseA + row) * DIM + kBase + sc8 * 8;
      const unsigned short* gB = E + (size_t)(rowBaseB + row) * DIM + kBase + sc8 * 8;
      __builtin_amdgcn_global_load_lds((const AS1 unsigned int*)gA,
                                       (AS3 unsigned int*)(lA + cb * 8), 16, 0, 0);
      __builtin_amdgcn_global_load_lds((const AS1 unsigned int*)gB,
                                       (AS3 unsigned int*)(lB + cb * 8), 16, 0, 0);
    }
    __syncthreads();

#pragma unroll
    for (int ks = 0; ks < 4; ks++) {           // 4 k-steps of 16
      bf16x8 af[2], bfv[2];
      const int c8 = ks * 2 + kg;
#pragma unroll
      for (int ti = 0; ti < 2; ti++) {
        int r = wr * 64 + ti * 32 + l31;
        af[ti] = *(const bf16x8*)(lA + (r * 8 + (c8 ^ (r & 7))) * 8);
      }
#pragma unroll
      for (int tj = 0; tj < 2; tj++) {
        int r = wc * 64 + tj * 32 + l31;
        bfv[tj] = *(const bf16x8*)(lB + (r * 8 + (c8 ^ (r & 7))) * 8);
      }
#pragma unroll
      for (int ti = 0; ti < 2; ti++)
#pragma unroll
        for (int tj = 0; tj < 2; tj++)
          acc[ti][tj] = __builtin_amdgcn_mfma_f32_32x32x16_bf16(
              af[ti], bfv[tj], acc[ti][tj], 0, 0, 0);
    }
    __syncthreads();
  }

  // per-block min/max
  float vmin = 3.4e38f, vmax = -3.4e38f;
#pragma unroll
  for (int ti = 0; ti < 2; ti++)
#pragma unroll
    for (int tj = 0; tj < 2; tj++)
#pragma unroll
      for (int r = 0; r < 16; r++) {
        float v = acc[ti][tj][r];
        vmin = fminf(vmin, v);
        vmax = fmaxf(vmax, v);
      }
#pragma unroll
  for (int m_ = 32; m_ >= 1; m_ >>= 1) {
    vmin = fminf(vmin, __shfl_xor(vmin, m_));
    vmax = fmaxf(vmax, __shfl_xor(vmax, m_));
  }
  if (lane == 0) redbuf[w] = make_float2(vmin, vmax);
  __syncthreads();
  if (tid == 0) {
    float mn = redbuf[0].x, mx = redbuf[0].y;
    for (int i = 1; i < 4; i++) {
      mn = fminf(mn, redbuf[i].x);
      mx = fmaxf(mx, redbuf[i].y);
    }
    partials[bi] = make_float2(mn, mx);
  }

  // diagonal tile: store raw 128x128 block (symmetric -> transpose-immune)
  if (tr == tc) {
    float* Bout = diagblocks + (size_t)tr * (128 * 128);
#pragma unroll
    for (int ti = 0; ti < 2; ti++) {
#pragma unroll
      for (int tj = 0; tj < 2; tj++) {
        int cbase = wc * 64 + tj * 32 + l31;   // C/D: col = lane & 31
#pragma unroll
        for (int r = 0; r < 16; r++) {
          int row = wr * 64 + ti * 32 + (r & 3) + 8 * (r >> 2) + 4 * kg;
          Bout[row * 128 + cbase] = acc[ti][tj][r];
        }
      }
    }
  }
}

// ---- kernel 3: fused global min/max reduce + gather + normalize ------------
__global__ __launch_bounds__(256) void k_finish(
    const float2* __restrict__ partials,
    const int* __restrict__ rix, const int* __restrict__ cix,
    const float* __restrict__ blocks, float* __restrict__ out, int n) {
  const int tid = threadIdx.x;
  float mn = 3.4e38f, mx = -3.4e38f;
  for (int i = tid; i < NPART; i += 256) {
    float2 p = partials[i];
    mn = fminf(mn, p.x);
    mx = fmaxf(mx, p.y);
  }
#pragma unroll
  for (int m_ = 32; m_ >= 1; m_ >>= 1) {
    mn = fminf(mn, __shfl_xor(mn, m_));
    mx = fmaxf(mx, __shfl_xor(mx, m_));
  }
  __shared__ float2 red[4];
  __shared__ float bcast[2];
  int w = tid >> 6, lane = tid & 63;
  if (lane == 0) red[w] = make_float2(mn, mx);
  __syncthreads();
  if (tid == 0) {
    for (int i = 1; i < 4; i++) {
      mn = fminf(mn, red[i].x);
      mx = fmaxf(mx, red[i].y);
    }
    bcast[0] = mn;
    bcast[1] = 1.0f / (mx - mn + 1e-7f);
  }
  __syncthreads();
  const float m = bcast[0], inv = bcast[1];

  const int stride = gridDim.x * blockDim.x;
  for (int i = blockIdx.x * blockDim.x + tid; i < n; i += stride) {
    int r = rix[i], c = cix[i];
    int g = r >> 7;
    float v = blocks[((size_t)g << 14) + ((r & 127) << 7) + (c & 127)];
    out[i] = (v - m) * inv;
  }
}

// ---------------------------------------------------------------------------
extern "C" void kernel_launch(void* const* d_in, const int* in_sizes, int n_in,
                              void* d_out, int out_size, void* d_ws, size_t ws_size,
                              hipStream_t stream) {
  const float* emb = (const float*)d_in[0];
  const int* rix   = (const int*)d_in[1];
  const int* cix   = (const int*)d_in[2];

  char* ws = (char*)d_ws;
  unsigned short* Ebf = (unsigned short*)(ws + 256);                      // 16 MB
  float2* partials    = (float2*)(ws + 256 + (16u << 20));                // 66 KB (pad 128K)
  float* diagblocks   = (float*)(ws + 256 + (16u << 20) + (128u << 10));  // 8 MB

  int n_elem = in_sizes[0];            // 16384*512
  int n4 = n_elem / 4;
  k_convert<<<(n4 + 255) / 256, 256, 0, stream>>>(emb, Ebf, n4);

  k_minmax_gemm<<<NPART, 256, 0, stream>>>(Ebf, partials, diagblocks);

  k_finish<<<256, 256, 0, stream>>>(partials, rix, cix, diagblocks,
                                    (float*)d_out, out_size);
}